// Round 3
// baseline (978.762 us; speedup 1.0000x reference)
//
#include <hip/hip_runtime.h>
#include <hip/hip_bf16.h>

#define D_DIM 512
#define P_DIM 1024
#define E_DIM 256
#define OUT_DIM 500

typedef __attribute__((ext_vector_type(8))) __bf16 bf16x8;
typedef __attribute__((ext_vector_type(4))) float f32x4;

__device__ __forceinline__ unsigned short f2bf(float f) {
    unsigned u = __builtin_bit_cast(unsigned, f);
    u += 0x7FFFu + ((u >> 16) & 1u);
    return (unsigned short)(u >> 16);
}

// ---------------- elementwise fp32 -> bf16 cast ----------------
__global__ void cast_bf16_kernel(const float* __restrict__ in,
                                 unsigned short* __restrict__ out, int n) {
    int i = blockIdx.x * 256 + threadIdx.x;
    if (i < n) out[i] = f2bf(in[i]);
}

// ---------------- transpose + cast (+zero-pad cols) ----------------
// in: [R][C] f32, out: [Cpad][R] bf16; out[c][r] = (c<C) ? in[r][c] : 0
__global__ void transpose_cast_kernel(const float* __restrict__ in,
                                      unsigned short* __restrict__ out,
                                      int R, int C, int Cpad) {
    __shared__ float tile[32][33];
    int c0 = blockIdx.x * 32, r0 = blockIdx.y * 32;
    #pragma unroll
    for (int s = 0; s < 32; s += 8) {
        int r = r0 + threadIdx.y + s, c = c0 + threadIdx.x;
        tile[threadIdx.y + s][threadIdx.x] = (r < R && c < C) ? in[r * C + c] : 0.f;
    }
    __syncthreads();
    #pragma unroll
    for (int s = 0; s < 32; s += 8) {
        int c = c0 + threadIdx.y + s, r = r0 + threadIdx.x;
        if (c < Cpad && r < R) out[c * R + r] = f2bf(tile[threadIdx.x][threadIdx.y + s]);
    }
}

__device__ __forceinline__ void store_out(float* p, float v) { *p = v; }
__device__ __forceinline__ void store_out(unsigned short* p, float v) { *p = f2bf(v); }

// ---------------- generic small GEMM: C = A @ Bt^T + bias ----------------
// A [M][K] bf16 row-major, Bt [N][K] bf16 (B transposed), bias fp32 [N] or null.
// 128x128 tile, BK=32, 4 waves (2x2 of 64x64), 16x16x32 bf16 MFMA.
template <typename OutT>
__global__ __launch_bounds__(256)
void gemm128_kernel(const unsigned short* __restrict__ A,
                    const unsigned short* __restrict__ Bt,
                    const float* __restrict__ bias,
                    OutT* __restrict__ Cd, int M, int N, int K) {
    __shared__ __align__(16) unsigned short As[128 * 40]; // stride 40: 2-way bank alias (free)
    __shared__ __align__(16) unsigned short Bs[128 * 40];
    const int t = threadIdx.x;
    const int m0 = blockIdx.x * 128, n0 = blockIdx.y * 128;
    const int r = t >> 1, kh = (t & 1) * 16;
    const int w = t >> 6, l = t & 63;
    const int wm = (w & 1) * 64, wn = (w >> 1) * 64;
    const int lr = l & 15, lq = l >> 4;

    f32x4 acc[4][4];
    #pragma unroll
    for (int a = 0; a < 4; a++)
        #pragma unroll
        for (int b = 0; b < 4; b++) acc[a][b] = (f32x4){0.f, 0.f, 0.f, 0.f};

    const unsigned short* aRow = &A[(m0 + r) * K];
    const unsigned short* bRow = &Bt[(n0 + r) * K];

    for (int k0 = 0; k0 < K; k0 += 32) {
        uint4 a0 = *reinterpret_cast<const uint4*>(&aRow[k0 + kh]);
        uint4 a1 = *reinterpret_cast<const uint4*>(&aRow[k0 + kh + 8]);
        uint4 b0 = *reinterpret_cast<const uint4*>(&bRow[k0 + kh]);
        uint4 b1 = *reinterpret_cast<const uint4*>(&bRow[k0 + kh + 8]);
        __syncthreads();
        *reinterpret_cast<uint4*>(&As[r * 40 + kh])     = a0;
        *reinterpret_cast<uint4*>(&As[r * 40 + kh + 8]) = a1;
        *reinterpret_cast<uint4*>(&Bs[r * 40 + kh])     = b0;
        *reinterpret_cast<uint4*>(&Bs[r * 40 + kh + 8]) = b1;
        __syncthreads();
        bf16x8 af[4], bfr[4];
        #pragma unroll
        for (int mi = 0; mi < 4; mi++)
            af[mi] = *reinterpret_cast<const bf16x8*>(&As[(wm + mi * 16 + lr) * 40 + lq * 8]);
        #pragma unroll
        for (int ni = 0; ni < 4; ni++)
            bfr[ni] = *reinterpret_cast<const bf16x8*>(&Bs[(wn + ni * 16 + lr) * 40 + lq * 8]);
        #pragma unroll
        for (int mi = 0; mi < 4; mi++)
            #pragma unroll
            for (int ni = 0; ni < 4; ni++)
                acc[mi][ni] = __builtin_amdgcn_mfma_f32_16x16x32_bf16(af[mi], bfr[ni], acc[mi][ni], 0, 0, 0);
    }

    #pragma unroll
    for (int ni = 0; ni < 4; ni++) {
        int n = n0 + wn + ni * 16 + lr;
        float bv = bias ? bias[n] : 0.f;
        #pragma unroll
        for (int mi = 0; mi < 4; mi++) {
            int m = m0 + wm + mi * 16 + lq * 4;
            #pragma unroll
            for (int rg = 0; rg < 4; rg++)
                store_out(&Cd[(m + rg) * N + n], acc[mi][ni][rg] + bv);
        }
    }
}

// ---------------- main fused pairwise-MLP GEMM (v3) ----------------
// One block per 128-pair M-tile. Phase 1: h[128][512] = relu(pp[i]+ee[j])
// computed ONCE into LDS (bf16, stride 520). Phase 2: BARRIER-FREE single
// K-pass; B fragments read directly from L2-resident w2t (512 KB); 8 waves
// as 2(M)x4(N) of 64x64, each wave covers both 256-wide N-halves via
// acc[4][8]. Epilogue once at the end (temporally clustered writes).
__global__ __launch_bounds__(512, 2)
void pair_mlp_kernel(const float* __restrict__ pp, const float* __restrict__ ee,
                     const unsigned short* __restrict__ w2t, // [512][512] bf16, rows n>=500 zero
                     const float* __restrict__ b2, float* __restrict__ out) {
    __shared__ __align__(16) unsigned short Hs[128 * 520]; // 133,120 B (only LDS user)

    const int t = threadIdx.x;
    const int mtile = blockIdx.x;       // 0..2047
    const int i = mtile >> 1;
    const int j0 = (mtile & 1) * 128;
    const long pairBase = (long)mtile * 128;

    // ---------- phase 1: h-gen (one time) ----------
    {
        const int rq = t >> 7;          // 0..3: row within 4-row group
        const int c4 = (t & 127) * 4;   // f32 column (0..508)
        const f32x4 pv = *reinterpret_cast<const f32x4*>(&pp[i * D_DIM + c4]);
        #pragma unroll 8
        for (int it = 0; it < 32; ++it) {
            int r = it * 4 + rq;
            f32x4 ev = *reinterpret_cast<const f32x4*>(&ee[(j0 + r) * D_DIM + c4]);
            f32x4 s = pv + ev;
            #pragma unroll
            for (int x = 0; x < 4; x++) s[x] = s[x] > 0.f ? s[x] : 0.f;
            unsigned u0, u1;
            asm("v_cvt_pk_bf16_f32 %0, %1, %2" : "=v"(u0) : "v"(s[0]), "v"(s[1]));
            asm("v_cvt_pk_bf16_f32 %0, %1, %2" : "=v"(u1) : "v"(s[2]), "v"(s[3]));
            uint2 hv; hv.x = u0; hv.y = u1;
            *reinterpret_cast<uint2*>(&Hs[r * 520 + c4]) = hv;
        }
    }
    __syncthreads();                    // Hs visible; the ONLY block barrier

    // ---------- phase 2: barrier-free K-loop ----------
    const int w = t >> 6, l = t & 63;
    const int wm = (w & 1) * 64;        // 0,64
    const int wn = (w >> 1) * 64;       // 0,64,128,192
    const int lr = l & 15, lq = l >> 4;

    f32x4 acc[4][8];
    #pragma unroll
    for (int a = 0; a < 4; a++)
        #pragma unroll
        for (int b = 0; b < 8; b++) acc[a][b] = (f32x4){0.f, 0.f, 0.f, 0.f};

    // B frag (ni): row n = (ni>>2)*256 + wn + (ni&3)*16 + lr ; k = k0 + lq*8
    const unsigned short* wBase = &w2t[(wn + lr) * D_DIM + lq * 8];

    for (int k0 = 0; k0 < D_DIM; k0 += 32) {
        bf16x8 af[4];
        #pragma unroll
        for (int mi = 0; mi < 4; mi++)
            af[mi] = *reinterpret_cast<const bf16x8*>(&Hs[(wm + mi * 16 + lr) * 520 + k0 + lq * 8]);
        bf16x8 bfr[8];
        #pragma unroll
        for (int ni = 0; ni < 8; ni++) {
            const int rowOff = (((ni >> 2) * 256) + (ni & 3) * 16) * D_DIM;
            bfr[ni] = *reinterpret_cast<const bf16x8*>(&wBase[rowOff + k0]);
        }
        #pragma unroll
        for (int mi = 0; mi < 4; mi++)
            #pragma unroll
            for (int ni = 0; ni < 8; ni++)
                acc[mi][ni] = __builtin_amdgcn_mfma_f32_16x16x32_bf16(af[mi], bfr[ni], acc[mi][ni], 0, 0, 0);
    }

    // ---------- epilogue: all 500 cols of each row written together ----------
    #pragma unroll
    for (int ni = 0; ni < 8; ni++) {
        int n = (ni >> 2) * 256 + wn + (ni & 3) * 16 + lr;
        if (n < OUT_DIM) {
            float bv = b2[n];
            #pragma unroll
            for (int mi = 0; mi < 4; mi++) {
                long m = pairBase + wm + mi * 16 + lq * 4;
                float* op = &out[m * OUT_DIM + n];
                #pragma unroll
                for (int rg = 0; rg < 4; rg++) {
                    float v = acc[mi][ni][rg] + bv;
                    op[(long)rg * OUT_DIM] = v > 0.f ? v : 0.f;
                }
            }
        }
    }
}

extern "C" void kernel_launch(void* const* d_in, const int* in_sizes, int n_in,
                              void* d_out, int out_size, void* d_ws, size_t ws_size,
                              hipStream_t stream) {
    const float* post  = (const float*)d_in[0];
    const float* emoji = (const float*)d_in[1];
    const float* k1_w  = (const float*)d_in[2];
    const float* k1_b  = (const float*)d_in[3];
    const float* k2_w  = (const float*)d_in[4];
    const float* k2_b  = (const float*)d_in[5];
    const float* l1_w  = (const float*)d_in[6];
    const float* l1_b  = (const float*)d_in[7];
    const float* l2_w  = (const float*)d_in[8];
    const float* l2_b  = (const float*)d_in[9];
    float* out = (float*)d_out;

    char* wp = (char*)d_ws;
    auto alloc = [&](size_t bytes) { char* q = wp; wp += (bytes + 255) & ~(size_t)255; return q; };
    unsigned short* post_bf  = (unsigned short*)alloc(P_DIM * D_DIM * 2);
    unsigned short* emoji_bf = (unsigned short*)alloc(E_DIM * D_DIM * 2);
    unsigned short* k1_wt    = (unsigned short*)alloc(D_DIM * D_DIM * 2);
    unsigned short* k2_wt    = (unsigned short*)alloc(D_DIM * D_DIM * 2);
    unsigned short* l1at     = (unsigned short*)alloc(D_DIM * D_DIM * 2);
    unsigned short* l1bt     = (unsigned short*)alloc(D_DIM * D_DIM * 2);
    unsigned short* w2t      = (unsigned short*)alloc(512 * 512 * 2);
    unsigned short* p_bf     = (unsigned short*)alloc(P_DIM * D_DIM * 2);
    unsigned short* e_bf     = (unsigned short*)alloc(E_DIM * D_DIM * 2);
    float* pp  = (float*)alloc(P_DIM * D_DIM * 4);
    float* eeb = (float*)alloc(E_DIM * D_DIM * 4);

    cast_bf16_kernel<<<P_DIM * D_DIM / 256, 256, 0, stream>>>(post, post_bf, P_DIM * D_DIM);
    cast_bf16_kernel<<<E_DIM * D_DIM / 256, 256, 0, stream>>>(emoji, emoji_bf, E_DIM * D_DIM);

    dim3 tb(32, 8);
    transpose_cast_kernel<<<dim3(16, 16), tb, 0, stream>>>(k1_w, k1_wt, 512, 512, 512);
    transpose_cast_kernel<<<dim3(16, 16), tb, 0, stream>>>(k2_w, k2_wt, 512, 512, 512);
    transpose_cast_kernel<<<dim3(16, 16), tb, 0, stream>>>(l1_w, l1at, 512, 512, 512);
    transpose_cast_kernel<<<dim3(16, 16), tb, 0, stream>>>(l1_w + 512 * 512, l1bt, 512, 512, 512);
    transpose_cast_kernel<<<dim3(16, 16), tb, 0, stream>>>(l2_w, w2t, 512, 500, 512);

    // p = post @ k1_w + k1_b  (bf16 out)
    gemm128_kernel<unsigned short><<<dim3(8, 4), 256, 0, stream>>>(post_bf, k1_wt, k1_b, p_bf, 1024, 512, 512);
    // e = emoji @ k2_w + k2_b (bf16 out)
    gemm128_kernel<unsigned short><<<dim3(2, 4), 256, 0, stream>>>(emoji_bf, k2_wt, k2_b, e_bf, 256, 512, 512);
    // pp = p @ l1_w[:512]     (f32 out)
    gemm128_kernel<float><<<dim3(8, 4), 256, 0, stream>>>(p_bf, l1at, (const float*)nullptr, pp, 1024, 512, 512);
    // ee = e @ l1_w[512:] + l1_b (f32 out; l1_b folded here)
    gemm128_kernel<float><<<dim3(2, 4), 256, 0, stream>>>(e_bf, l1bt, l1_b, eeb, 256, 512, 512);

    // out[i,j,:] = relu(relu(pp[i]+ee[j]) @ w2 + b2)
    pair_mlp_kernel<<<dim3(2048), 512, 0, stream>>>(pp, eeb, w2t, l2_b, out);
}

// Round 4
// 887.830 us; speedup vs baseline: 1.1024x; 1.1024x over previous
//
#include <hip/hip_runtime.h>
#include <hip/hip_bf16.h>

#define D_DIM 512
#define P_DIM 1024
#define E_DIM 256
#define OUT_DIM 500

typedef __attribute__((ext_vector_type(8))) __bf16 bf16x8;
typedef __attribute__((ext_vector_type(4))) float f32x4;

__device__ __forceinline__ unsigned short f2bf(float f) {
    unsigned u = __builtin_bit_cast(unsigned, f);
    u += 0x7FFFu + ((u >> 16) & 1u);
    return (unsigned short)(u >> 16);
}

// ---------------- elementwise fp32 -> bf16 cast ----------------
__global__ void cast_bf16_kernel(const float* __restrict__ in,
                                 unsigned short* __restrict__ out, int n) {
    int i = blockIdx.x * 256 + threadIdx.x;
    if (i < n) out[i] = f2bf(in[i]);
}

// ---------------- transpose + cast (+zero-pad cols) ----------------
// in: [R][C] f32, out: [Cpad][R] bf16; out[c][r] = (c<C) ? in[r][c] : 0
__global__ void transpose_cast_kernel(const float* __restrict__ in,
                                      unsigned short* __restrict__ out,
                                      int R, int C, int Cpad) {
    __shared__ float tile[32][33];
    int c0 = blockIdx.x * 32, r0 = blockIdx.y * 32;
    #pragma unroll
    for (int s = 0; s < 32; s += 8) {
        int r = r0 + threadIdx.y + s, c = c0 + threadIdx.x;
        tile[threadIdx.y + s][threadIdx.x] = (r < R && c < C) ? in[r * C + c] : 0.f;
    }
    __syncthreads();
    #pragma unroll
    for (int s = 0; s < 32; s += 8) {
        int c = c0 + threadIdx.y + s, r = r0 + threadIdx.x;
        if (c < Cpad && r < R) out[c * R + r] = f2bf(tile[threadIdx.x][threadIdx.y + s]);
    }
}

__device__ __forceinline__ void store_out(float* p, float v) { *p = v; }
__device__ __forceinline__ void store_out(unsigned short* p, float v) { *p = f2bf(v); }

// ---------------- generic small GEMM: C = A @ Bt^T + bias ----------------
// A [M][K] bf16 row-major, Bt [N][K] bf16 (B transposed), bias fp32 [N] or null.
// 128x128 tile, BK=32, 4 waves (2x2 of 64x64), 16x16x32 bf16 MFMA.
template <typename OutT>
__global__ __launch_bounds__(256)
void gemm128_kernel(const unsigned short* __restrict__ A,
                    const unsigned short* __restrict__ Bt,
                    const float* __restrict__ bias,
                    OutT* __restrict__ Cd, int M, int N, int K) {
    __shared__ __align__(16) unsigned short As[128 * 40]; // stride 40: 2-way bank alias (free)
    __shared__ __align__(16) unsigned short Bs[128 * 40];
    const int t = threadIdx.x;
    const int m0 = blockIdx.x * 128, n0 = blockIdx.y * 128;
    const int r = t >> 1, kh = (t & 1) * 16;
    const int w = t >> 6, l = t & 63;
    const int wm = (w & 1) * 64, wn = (w >> 1) * 64;
    const int lr = l & 15, lq = l >> 4;

    f32x4 acc[4][4];
    #pragma unroll
    for (int a = 0; a < 4; a++)
        #pragma unroll
        for (int b = 0; b < 4; b++) acc[a][b] = (f32x4){0.f, 0.f, 0.f, 0.f};

    const unsigned short* aRow = &A[(m0 + r) * K];
    const unsigned short* bRow = &Bt[(n0 + r) * K];

    for (int k0 = 0; k0 < K; k0 += 32) {
        uint4 a0 = *reinterpret_cast<const uint4*>(&aRow[k0 + kh]);
        uint4 a1 = *reinterpret_cast<const uint4*>(&aRow[k0 + kh + 8]);
        uint4 b0 = *reinterpret_cast<const uint4*>(&bRow[k0 + kh]);
        uint4 b1 = *reinterpret_cast<const uint4*>(&bRow[k0 + kh + 8]);
        __syncthreads();
        *reinterpret_cast<uint4*>(&As[r * 40 + kh])     = a0;
        *reinterpret_cast<uint4*>(&As[r * 40 + kh + 8]) = a1;
        *reinterpret_cast<uint4*>(&Bs[r * 40 + kh])     = b0;
        *reinterpret_cast<uint4*>(&Bs[r * 40 + kh + 8]) = b1;
        __syncthreads();
        bf16x8 af[4], bfr[4];
        #pragma unroll
        for (int mi = 0; mi < 4; mi++)
            af[mi] = *reinterpret_cast<const bf16x8*>(&As[(wm + mi * 16 + lr) * 40 + lq * 8]);
        #pragma unroll
        for (int ni = 0; ni < 4; ni++)
            bfr[ni] = *reinterpret_cast<const bf16x8*>(&Bs[(wn + ni * 16 + lr) * 40 + lq * 8]);
        #pragma unroll
        for (int mi = 0; mi < 4; mi++)
            #pragma unroll
            for (int ni = 0; ni < 4; ni++)
                acc[mi][ni] = __builtin_amdgcn_mfma_f32_16x16x32_bf16(af[mi], bfr[ni], acc[mi][ni], 0, 0, 0);
    }

    #pragma unroll
    for (int ni = 0; ni < 4; ni++) {
        int n = n0 + wn + ni * 16 + lr;
        float bv = bias ? bias[n] : 0.f;
        #pragma unroll
        for (int mi = 0; mi < 4; mi++) {
            int m = m0 + wm + mi * 16 + lq * 4;
            #pragma unroll
            for (int rg = 0; rg < 4; rg++)
                store_out(&Cd[(m + rg) * N + n], acc[mi][ni][rg] + bv);
        }
    }
}

// ---------------- main fused pairwise-MLP GEMM ----------------
// Virtual A row (pair = i*256 + j): h[k] = relu(pp[i][k] + ee[j][k])  (l1_b folded into ee)
// out[pair][n] = relu(sum_k h[k]*w2[k][n] + b2[n]).
// M-tile = 128 pairs (one i, 128 consecutive j), N-tile = 128, BK = 32.
// v4: identical to the 355us baseline except pack2 (-~9 VALU ops per 2 vals)
//     replaced by v_cvt_pk_bf16_f32 (1 op per 2 vals, same RNE rounding).
__global__ __launch_bounds__(256)
void pair_mlp_kernel(const float* __restrict__ pp, const float* __restrict__ ee,
                     const unsigned short* __restrict__ w2t, // [512][512] bf16, rows n>=500 zero
                     const float* __restrict__ b2, float* __restrict__ out) {
    __shared__ __align__(16) unsigned short As[128 * 40];
    __shared__ __align__(16) unsigned short Bs[128 * 40];
    __shared__ float pps[D_DIM];

    const int t = threadIdx.x;
    const int mtile = blockIdx.x;       // 0..2047
    const int n0 = blockIdx.y * 128;    // 0,128,256,384
    const int i = mtile >> 1;
    const int j0 = (mtile & 1) * 128;
    const long pairBase = (long)mtile * 128;

    const int r = t >> 1, kh = (t & 1) * 16;
    const int w = t >> 6, l = t & 63;
    const int wm = (w & 1) * 64, wn = (w >> 1) * 64;
    const int lr = l & 15, lq = l >> 4;

    // stage this block's pp row once (broadcast source for h-gen)
    pps[t] = pp[i * D_DIM + t];
    pps[t + 256] = pp[i * D_DIM + t + 256];

    f32x4 acc[4][4];
    #pragma unroll
    for (int a = 0; a < 4; a++)
        #pragma unroll
        for (int b = 0; b < 4; b++) acc[a][b] = (f32x4){0.f, 0.f, 0.f, 0.f};

    const float* eeRow = &ee[(j0 + r) * D_DIM];
    const unsigned short* wRow = &w2t[(n0 + r) * D_DIM];

    for (int k0 = 0; k0 < D_DIM; k0 += 32) {
        f32x4 ev0 = *reinterpret_cast<const f32x4*>(&eeRow[k0 + kh]);
        f32x4 ev1 = *reinterpret_cast<const f32x4*>(&eeRow[k0 + kh + 4]);
        f32x4 ev2 = *reinterpret_cast<const f32x4*>(&eeRow[k0 + kh + 8]);
        f32x4 ev3 = *reinterpret_cast<const f32x4*>(&eeRow[k0 + kh + 12]);
        uint4 wv0 = *reinterpret_cast<const uint4*>(&wRow[k0 + kh]);
        uint4 wv1 = *reinterpret_cast<const uint4*>(&wRow[k0 + kh + 8]);
        __syncthreads();  // prev-iter LDS reads done; pps ready on iter 0
        f32x4 pv0 = *reinterpret_cast<const f32x4*>(&pps[k0 + kh]);
        f32x4 pv1 = *reinterpret_cast<const f32x4*>(&pps[k0 + kh + 4]);
        f32x4 pv2 = *reinterpret_cast<const f32x4*>(&pps[k0 + kh + 8]);
        f32x4 pv3 = *reinterpret_cast<const f32x4*>(&pps[k0 + kh + 12]);
        f32x4 s0 = pv0 + ev0, s1 = pv1 + ev1, s2 = pv2 + ev2, s3 = pv3 + ev3;
        #pragma unroll
        for (int x = 0; x < 4; x++) {
            s0[x] = s0[x] > 0.f ? s0[x] : 0.f;
            s1[x] = s1[x] > 0.f ? s1[x] : 0.f;
            s2[x] = s2[x] > 0.f ? s2[x] : 0.f;
            s3[x] = s3[x] > 0.f ? s3[x] : 0.f;
        }
        uint4 h0, h1;
        asm("v_cvt_pk_bf16_f32 %0, %1, %2" : "=v"(h0.x) : "v"(s0[0]), "v"(s0[1]));
        asm("v_cvt_pk_bf16_f32 %0, %1, %2" : "=v"(h0.y) : "v"(s0[2]), "v"(s0[3]));
        asm("v_cvt_pk_bf16_f32 %0, %1, %2" : "=v"(h0.z) : "v"(s1[0]), "v"(s1[1]));
        asm("v_cvt_pk_bf16_f32 %0, %1, %2" : "=v"(h0.w) : "v"(s1[2]), "v"(s1[3]));
        asm("v_cvt_pk_bf16_f32 %0, %1, %2" : "=v"(h1.x) : "v"(s2[0]), "v"(s2[1]));
        asm("v_cvt_pk_bf16_f32 %0, %1, %2" : "=v"(h1.y) : "v"(s2[2]), "v"(s2[3]));
        asm("v_cvt_pk_bf16_f32 %0, %1, %2" : "=v"(h1.z) : "v"(s3[0]), "v"(s3[1]));
        asm("v_cvt_pk_bf16_f32 %0, %1, %2" : "=v"(h1.w) : "v"(s3[2]), "v"(s3[3]));
        *reinterpret_cast<uint4*>(&As[r * 40 + kh])     = h0;
        *reinterpret_cast<uint4*>(&As[r * 40 + kh + 8]) = h1;
        *reinterpret_cast<uint4*>(&Bs[r * 40 + kh])     = wv0;
        *reinterpret_cast<uint4*>(&Bs[r * 40 + kh + 8]) = wv1;
        __syncthreads();
        bf16x8 af[4], bfr[4];
        #pragma unroll
        for (int mi = 0; mi < 4; mi++)
            af[mi] = *reinterpret_cast<const bf16x8*>(&As[(wm + mi * 16 + lr) * 40 + lq * 8]);
        #pragma unroll
        for (int ni = 0; ni < 4; ni++)
            bfr[ni] = *reinterpret_cast<const bf16x8*>(&Bs[(wn + ni * 16 + lr) * 40 + lq * 8]);
        #pragma unroll
        for (int mi = 0; mi < 4; mi++)
            #pragma unroll
            for (int ni = 0; ni < 4; ni++)
                acc[mi][ni] = __builtin_amdgcn_mfma_f32_16x16x32_bf16(af[mi], bfr[ni], acc[mi][ni], 0, 0, 0);
    }

    #pragma unroll
    for (int ni = 0; ni < 4; ni++) {
        int n = n0 + wn + ni * 16 + lr;
        bool valid = n < OUT_DIM;
        float bv = valid ? b2[n] : 0.f;
        #pragma unroll
        for (int mi = 0; mi < 4; mi++) {
            int row = wm + mi * 16 + lq * 4;
            float* op = &out[(pairBase + row) * OUT_DIM + n];
            if (valid) {
                #pragma unroll
                for (int rg = 0; rg < 4; rg++) {
                    float v = acc[mi][ni][rg] + bv;
                    op[(long)rg * OUT_DIM] = v > 0.f ? v : 0.f;
                }
            }
        }
    }
}

extern "C" void kernel_launch(void* const* d_in, const int* in_sizes, int n_in,
                              void* d_out, int out_size, void* d_ws, size_t ws_size,
                              hipStream_t stream) {
    const float* post  = (const float*)d_in[0];
    const float* emoji = (const float*)d_in[1];
    const float* k1_w  = (const float*)d_in[2];
    const float* k1_b  = (const float*)d_in[3];
    const float* k2_w  = (const float*)d_in[4];
    const float* k2_b  = (const float*)d_in[5];
    const float* l1_w  = (const float*)d_in[6];
    const float* l1_b  = (const float*)d_in[7];
    const float* l2_w  = (const float*)d_in[8];
    const float* l2_b  = (const float*)d_in[9];
    float* out = (float*)d_out;

    char* wp = (char*)d_ws;
    auto alloc = [&](size_t bytes) { char* q = wp; wp += (bytes + 255) & ~(size_t)255; return q; };
    unsigned short* post_bf  = (unsigned short*)alloc(P_DIM * D_DIM * 2);
    unsigned short* emoji_bf = (unsigned short*)alloc(E_DIM * D_DIM * 2);
    unsigned short* k1_wt    = (unsigned short*)alloc(D_DIM * D_DIM * 2);
    unsigned short* k2_wt    = (unsigned short*)alloc(D_DIM * D_DIM * 2);
    unsigned short* l1at     = (unsigned short*)alloc(D_DIM * D_DIM * 2);
    unsigned short* l1bt     = (unsigned short*)alloc(D_DIM * D_DIM * 2);
    unsigned short* w2t      = (unsigned short*)alloc(512 * 512 * 2);
    unsigned short* p_bf     = (unsigned short*)alloc(P_DIM * D_DIM * 2);
    unsigned short* e_bf     = (unsigned short*)alloc(E_DIM * D_DIM * 2);
    float* pp  = (float*)alloc(P_DIM * D_DIM * 4);
    float* eeb = (float*)alloc(E_DIM * D_DIM * 4);

    cast_bf16_kernel<<<P_DIM * D_DIM / 256, 256, 0, stream>>>(post, post_bf, P_DIM * D_DIM);
    cast_bf16_kernel<<<E_DIM * D_DIM / 256, 256, 0, stream>>>(emoji, emoji_bf, E_DIM * D_DIM);

    dim3 tb(32, 8);
    transpose_cast_kernel<<<dim3(16, 16), tb, 0, stream>>>(k1_w, k1_wt, 512, 512, 512);
    transpose_cast_kernel<<<dim3(16, 16), tb, 0, stream>>>(k2_w, k2_wt, 512, 512, 512);
    transpose_cast_kernel<<<dim3(16, 16), tb, 0, stream>>>(l1_w, l1at, 512, 512, 512);
    transpose_cast_kernel<<<dim3(16, 16), tb, 0, stream>>>(l1_w + 512 * 512, l1bt, 512, 512, 512);
    transpose_cast_kernel<<<dim3(16, 16), tb, 0, stream>>>(l2_w, w2t, 512, 500, 512);

    // p = post @ k1_w + k1_b  (bf16 out)
    gemm128_kernel<unsigned short><<<dim3(8, 4), 256, 0, stream>>>(post_bf, k1_wt, k1_b, p_bf, 1024, 512, 512);
    // e = emoji @ k2_w + k2_b (bf16 out)
    gemm128_kernel<unsigned short><<<dim3(2, 4), 256, 0, stream>>>(emoji_bf, k2_wt, k2_b, e_bf, 256, 512, 512);
    // pp = p @ l1_w[:512]     (f32 out)
    gemm128_kernel<float><<<dim3(8, 4), 256, 0, stream>>>(p_bf, l1at, (const float*)nullptr, pp, 1024, 512, 512);
    // ee = e @ l1_w[512:] + l1_b (f32 out; l1_b folded here)
    gemm128_kernel<float><<<dim3(2, 4), 256, 0, stream>>>(e_bf, l1bt, l1_b, eeb, 256, 512, 512);

    // out[i,j,:] = relu(relu(pp[i]+ee[j]) @ w2 + b2)
    pair_mlp_kernel<<<dim3(2048, 4), 256, 0, stream>>>(pp, eeb, w2t, l2_b, out);
}

// Round 5
// 864.944 us; speedup vs baseline: 1.1316x; 1.0265x over previous
//
#include <hip/hip_runtime.h>
#include <hip/hip_bf16.h>

#define D_DIM 512
#define P_DIM 1024
#define E_DIM 256
#define OUT_DIM 500

typedef __attribute__((ext_vector_type(8))) __bf16 bf16x8;
typedef __attribute__((ext_vector_type(4))) float f32x4;

__device__ __forceinline__ unsigned short f2bf(float f) {
    unsigned u = __builtin_bit_cast(unsigned, f);
    u += 0x7FFFu + ((u >> 16) & 1u);
    return (unsigned short)(u >> 16);
}

// ---------------- elementwise fp32 -> bf16 cast ----------------
__global__ void cast_bf16_kernel(const float* __restrict__ in,
                                 unsigned short* __restrict__ out, int n) {
    int i = blockIdx.x * 256 + threadIdx.x;
    if (i < n) out[i] = f2bf(in[i]);
}

// ---------------- transpose + cast (+zero-pad cols) ----------------
// in: [R][C] f32, out: [Cpad][R] bf16; out[c][r] = (c<C) ? in[r][c] : 0
__global__ void transpose_cast_kernel(const float* __restrict__ in,
                                      unsigned short* __restrict__ out,
                                      int R, int C, int Cpad) {
    __shared__ float tile[32][33];
    int c0 = blockIdx.x * 32, r0 = blockIdx.y * 32;
    #pragma unroll
    for (int s = 0; s < 32; s += 8) {
        int r = r0 + threadIdx.y + s, c = c0 + threadIdx.x;
        tile[threadIdx.y + s][threadIdx.x] = (r < R && c < C) ? in[r * C + c] : 0.f;
    }
    __syncthreads();
    #pragma unroll
    for (int s = 0; s < 32; s += 8) {
        int c = c0 + threadIdx.y + s, r = r0 + threadIdx.x;
        if (c < Cpad && r < R) out[c * R + r] = f2bf(tile[threadIdx.x][threadIdx.y + s]);
    }
}

__device__ __forceinline__ void store_out(float* p, float v) { *p = v; }
__device__ __forceinline__ void store_out(unsigned short* p, float v) { *p = f2bf(v); }

// ---------------- generic small GEMM: C = A @ Bt^T + bias ----------------
// A [M][K] bf16 row-major, Bt [N][K] bf16 (B transposed), bias fp32 [N] or null.
// 128x128 tile, BK=32, 4 waves (2x2 of 64x64), 16x16x32 bf16 MFMA.
template <typename OutT>
__global__ __launch_bounds__(256)
void gemm128_kernel(const unsigned short* __restrict__ A,
                    const unsigned short* __restrict__ Bt,
                    const float* __restrict__ bias,
                    OutT* __restrict__ Cd, int M, int N, int K) {
    __shared__ __align__(16) unsigned short As[128 * 40]; // stride 40: 2-way bank alias (free)
    __shared__ __align__(16) unsigned short Bs[128 * 40];
    const int t = threadIdx.x;
    const int m0 = blockIdx.x * 128, n0 = blockIdx.y * 128;
    const int r = t >> 1, kh = (t & 1) * 16;
    const int w = t >> 6, l = t & 63;
    const int wm = (w & 1) * 64, wn = (w >> 1) * 64;
    const int lr = l & 15, lq = l >> 4;

    f32x4 acc[4][4];
    #pragma unroll
    for (int a = 0; a < 4; a++)
        #pragma unroll
        for (int b = 0; b < 4; b++) acc[a][b] = (f32x4){0.f, 0.f, 0.f, 0.f};

    const unsigned short* aRow = &A[(m0 + r) * K];
    const unsigned short* bRow = &Bt[(n0 + r) * K];

    for (int k0 = 0; k0 < K; k0 += 32) {
        uint4 a0 = *reinterpret_cast<const uint4*>(&aRow[k0 + kh]);
        uint4 a1 = *reinterpret_cast<const uint4*>(&aRow[k0 + kh + 8]);
        uint4 b0 = *reinterpret_cast<const uint4*>(&bRow[k0 + kh]);
        uint4 b1 = *reinterpret_cast<const uint4*>(&bRow[k0 + kh + 8]);
        __syncthreads();
        *reinterpret_cast<uint4*>(&As[r * 40 + kh])     = a0;
        *reinterpret_cast<uint4*>(&As[r * 40 + kh + 8]) = a1;
        *reinterpret_cast<uint4*>(&Bs[r * 40 + kh])     = b0;
        *reinterpret_cast<uint4*>(&Bs[r * 40 + kh + 8]) = b1;
        __syncthreads();
        bf16x8 af[4], bfr[4];
        #pragma unroll
        for (int mi = 0; mi < 4; mi++)
            af[mi] = *reinterpret_cast<const bf16x8*>(&As[(wm + mi * 16 + lr) * 40 + lq * 8]);
        #pragma unroll
        for (int ni = 0; ni < 4; ni++)
            bfr[ni] = *reinterpret_cast<const bf16x8*>(&Bs[(wn + ni * 16 + lr) * 40 + lq * 8]);
        #pragma unroll
        for (int mi = 0; mi < 4; mi++)
            #pragma unroll
            for (int ni = 0; ni < 4; ni++)
                acc[mi][ni] = __builtin_amdgcn_mfma_f32_16x16x32_bf16(af[mi], bfr[ni], acc[mi][ni], 0, 0, 0);
    }

    #pragma unroll
    for (int ni = 0; ni < 4; ni++) {
        int n = n0 + wn + ni * 16 + lr;
        float bv = bias ? bias[n] : 0.f;
        #pragma unroll
        for (int mi = 0; mi < 4; mi++) {
            int m = m0 + wm + mi * 16 + lq * 4;
            #pragma unroll
            for (int rg = 0; rg < 4; rg++)
                store_out(&Cd[(m + rg) * N + n], acc[mi][ni][rg] + bv);
        }
    }
}

// ---------------- main fused pairwise-MLP GEMM ----------------
// v5: same tiles/grid/epilogue as the 355us baseline (v4), but the K-loop is
// software-pipelined: double-buffered As/Bs (ONE barrier per k-step) and
// global ee/w2t loads issued TWO steps ahead so L2 latency hides under
// MFMA + frag reads. h-gen VALU for step s+1 runs after step s's MFMAs.
__global__ __launch_bounds__(256)
void pair_mlp_kernel(const float* __restrict__ pp, const float* __restrict__ ee,
                     const unsigned short* __restrict__ w2t, // [512][512] bf16, rows n>=500 zero
                     const float* __restrict__ b2, float* __restrict__ out) {
    __shared__ __align__(16) unsigned short As[2][128 * 40]; // 2 x 10,240 B
    __shared__ __align__(16) unsigned short Bs[2][128 * 40]; // 2 x 10,240 B
    __shared__ float pps[D_DIM];                             // 2,048 B (total 43 KB)

    const int t = threadIdx.x;
    const int mtile = blockIdx.x;       // 0..2047
    const int n0 = blockIdx.y * 128;    // 0,128,256,384
    const int i = mtile >> 1;
    const int j0 = (mtile & 1) * 128;
    const long pairBase = (long)mtile * 128;

    const int r = t >> 1, kh = (t & 1) * 16;
    const int w = t >> 6, l = t & 63;
    const int wm = (w & 1) * 64, wn = (w >> 1) * 64;
    const int lr = l & 15, lq = l >> 4;

    // stage this block's pp row once (broadcast source for h-gen)
    pps[t] = pp[i * D_DIM + t];
    pps[t + 256] = pp[i * D_DIM + t + 256];

    f32x4 acc[4][4];
    #pragma unroll
    for (int a = 0; a < 4; a++)
        #pragma unroll
        for (int b = 0; b < 4; b++) acc[a][b] = (f32x4){0.f, 0.f, 0.f, 0.f};

    const float* eeRow = &ee[(j0 + r) * D_DIM];
    const unsigned short* wRow = &w2t[(n0 + r) * D_DIM];

    f32x4 ev0, ev1, ev2, ev3;   // staged ee values (f32) for the NEXT h-gen
    uint4 wv0, wv1;             // staged w2t values for the NEXT Bs write

#define LOADK(K0) do {                                                        \
        ev0 = *reinterpret_cast<const f32x4*>(&eeRow[(K0) + kh]);             \
        ev1 = *reinterpret_cast<const f32x4*>(&eeRow[(K0) + kh + 4]);         \
        ev2 = *reinterpret_cast<const f32x4*>(&eeRow[(K0) + kh + 8]);         \
        ev3 = *reinterpret_cast<const f32x4*>(&eeRow[(K0) + kh + 12]);        \
        wv0 = *reinterpret_cast<const uint4*>(&wRow[(K0) + kh]);              \
        wv1 = *reinterpret_cast<const uint4*>(&wRow[(K0) + kh + 8]);          \
    } while (0)

#define HGEN_WRITE(BUF, K0) do {                                              \
        f32x4 pv0 = *reinterpret_cast<const f32x4*>(&pps[(K0) + kh]);         \
        f32x4 pv1 = *reinterpret_cast<const f32x4*>(&pps[(K0) + kh + 4]);     \
        f32x4 pv2 = *reinterpret_cast<const f32x4*>(&pps[(K0) + kh + 8]);     \
        f32x4 pv3 = *reinterpret_cast<const f32x4*>(&pps[(K0) + kh + 12]);    \
        f32x4 s0 = pv0 + ev0, s1 = pv1 + ev1, s2 = pv2 + ev2, s3 = pv3 + ev3; \
        _Pragma("unroll")                                                     \
        for (int x = 0; x < 4; x++) {                                         \
            s0[x] = s0[x] > 0.f ? s0[x] : 0.f;                                \
            s1[x] = s1[x] > 0.f ? s1[x] : 0.f;                                \
            s2[x] = s2[x] > 0.f ? s2[x] : 0.f;                                \
            s3[x] = s3[x] > 0.f ? s3[x] : 0.f;                                \
        }                                                                     \
        uint4 h0, h1;                                                         \
        asm("v_cvt_pk_bf16_f32 %0, %1, %2" : "=v"(h0.x) : "v"(s0[0]), "v"(s0[1])); \
        asm("v_cvt_pk_bf16_f32 %0, %1, %2" : "=v"(h0.y) : "v"(s0[2]), "v"(s0[3])); \
        asm("v_cvt_pk_bf16_f32 %0, %1, %2" : "=v"(h0.z) : "v"(s1[0]), "v"(s1[1])); \
        asm("v_cvt_pk_bf16_f32 %0, %1, %2" : "=v"(h0.w) : "v"(s1[2]), "v"(s1[3])); \
        asm("v_cvt_pk_bf16_f32 %0, %1, %2" : "=v"(h1.x) : "v"(s2[0]), "v"(s2[1])); \
        asm("v_cvt_pk_bf16_f32 %0, %1, %2" : "=v"(h1.y) : "v"(s2[2]), "v"(s2[3])); \
        asm("v_cvt_pk_bf16_f32 %0, %1, %2" : "=v"(h1.z) : "v"(s3[0]), "v"(s3[1])); \
        asm("v_cvt_pk_bf16_f32 %0, %1, %2" : "=v"(h1.w) : "v"(s3[2]), "v"(s3[3])); \
        *reinterpret_cast<uint4*>(&As[BUF][r * 40 + kh])     = h0;            \
        *reinterpret_cast<uint4*>(&As[BUF][r * 40 + kh + 8]) = h1;            \
        *reinterpret_cast<uint4*>(&Bs[BUF][r * 40 + kh])     = wv0;           \
        *reinterpret_cast<uint4*>(&Bs[BUF][r * 40 + kh + 8]) = wv1;           \
    } while (0)

    // ---- pipeline prologue ----
    LOADK(0);
    __syncthreads();            // pps visible
    HGEN_WRITE(0, 0);           // buf0 <- k=0
    LOADK(32);                  // prefetch step-1 data into regs
    __syncthreads();            // buf0 visible

    // ---- main loop: one barrier per k-step ----
    for (int s = 0; s < 16; ++s) {
        const int cur = s & 1;
        bf16x8 af[4], bfr[4];
        #pragma unroll
        for (int mi = 0; mi < 4; mi++)
            af[mi] = *reinterpret_cast<const bf16x8*>(&As[cur][(wm + mi * 16 + lr) * 40 + lq * 8]);
        #pragma unroll
        for (int ni = 0; ni < 4; ni++)
            bfr[ni] = *reinterpret_cast<const bf16x8*>(&Bs[cur][(wn + ni * 16 + lr) * 40 + lq * 8]);
        #pragma unroll
        for (int mi = 0; mi < 4; mi++)
            #pragma unroll
            for (int ni = 0; ni < 4; ni++)
                acc[mi][ni] = __builtin_amdgcn_mfma_f32_16x16x32_bf16(af[mi], bfr[ni], acc[mi][ni], 0, 0, 0);

        if (s < 15) {
            HGEN_WRITE(cur ^ 1, (s + 1) * 32);   // consume staged regs -> buf^1
            if (s < 14) LOADK((s + 2) * 32);     // prefetch two steps ahead
        }
        __syncthreads();        // buf^1 writes visible; buf[cur] reads done
    }
#undef LOADK
#undef HGEN_WRITE

    #pragma unroll
    for (int ni = 0; ni < 4; ni++) {
        int n = n0 + wn + ni * 16 + lr;
        bool valid = n < OUT_DIM;
        float bv = valid ? b2[n] : 0.f;
        #pragma unroll
        for (int mi = 0; mi < 4; mi++) {
            int row = wm + mi * 16 + lq * 4;
            float* op = &out[(pairBase + row) * OUT_DIM + n];
            if (valid) {
                #pragma unroll
                for (int rg = 0; rg < 4; rg++) {
                    float v = acc[mi][ni][rg] + bv;
                    op[(long)rg * OUT_DIM] = v > 0.f ? v : 0.f;
                }
            }
        }
    }
}

extern "C" void kernel_launch(void* const* d_in, const int* in_sizes, int n_in,
                              void* d_out, int out_size, void* d_ws, size_t ws_size,
                              hipStream_t stream) {
    const float* post  = (const float*)d_in[0];
    const float* emoji = (const float*)d_in[1];
    const float* k1_w  = (const float*)d_in[2];
    const float* k1_b  = (const float*)d_in[3];
    const float* k2_w  = (const float*)d_in[4];
    const float* k2_b  = (const float*)d_in[5];
    const float* l1_w  = (const float*)d_in[6];
    const float* l1_b  = (const float*)d_in[7];
    const float* l2_w  = (const float*)d_in[8];
    const float* l2_b  = (const float*)d_in[9];
    float* out = (float*)d_out;

    char* wp = (char*)d_ws;
    auto alloc = [&](size_t bytes) { char* q = wp; wp += (bytes + 255) & ~(size_t)255; return q; };
    unsigned short* post_bf  = (unsigned short*)alloc(P_DIM * D_DIM * 2);
    unsigned short* emoji_bf = (unsigned short*)alloc(E_DIM * D_DIM * 2);
    unsigned short* k1_wt    = (unsigned short*)alloc(D_DIM * D_DIM * 2);
    unsigned short* k2_wt    = (unsigned short*)alloc(D_DIM * D_DIM * 2);
    unsigned short* l1at     = (unsigned short*)alloc(D_DIM * D_DIM * 2);
    unsigned short* l1bt     = (unsigned short*)alloc(D_DIM * D_DIM * 2);
    unsigned short* w2t      = (unsigned short*)alloc(512 * 512 * 2);
    unsigned short* p_bf     = (unsigned short*)alloc(P_DIM * D_DIM * 2);
    unsigned short* e_bf     = (unsigned short*)alloc(E_DIM * D_DIM * 2);
    float* pp  = (float*)alloc(P_DIM * D_DIM * 4);
    float* eeb = (float*)alloc(E_DIM * D_DIM * 4);

    cast_bf16_kernel<<<P_DIM * D_DIM / 256, 256, 0, stream>>>(post, post_bf, P_DIM * D_DIM);
    cast_bf16_kernel<<<E_DIM * D_DIM / 256, 256, 0, stream>>>(emoji, emoji_bf, E_DIM * D_DIM);

    dim3 tb(32, 8);
    transpose_cast_kernel<<<dim3(16, 16), tb, 0, stream>>>(k1_w, k1_wt, 512, 512, 512);
    transpose_cast_kernel<<<dim3(16, 16), tb, 0, stream>>>(k2_w, k2_wt, 512, 512, 512);
    transpose_cast_kernel<<<dim3(16, 16), tb, 0, stream>>>(l1_w, l1at, 512, 512, 512);
    transpose_cast_kernel<<<dim3(16, 16), tb, 0, stream>>>(l1_w + 512 * 512, l1bt, 512, 512, 512);
    transpose_cast_kernel<<<dim3(16, 16), tb, 0, stream>>>(l2_w, w2t, 512, 500, 512);

    // p = post @ k1_w + k1_b  (bf16 out)
    gemm128_kernel<unsigned short><<<dim3(8, 4), 256, 0, stream>>>(post_bf, k1_wt, k1_b, p_bf, 1024, 512, 512);
    // e = emoji @ k2_w + k2_b (bf16 out)
    gemm128_kernel<unsigned short><<<dim3(2, 4), 256, 0, stream>>>(emoji_bf, k2_wt, k2_b, e_bf, 256, 512, 512);
    // pp = p @ l1_w[:512]     (f32 out)
    gemm128_kernel<float><<<dim3(8, 4), 256, 0, stream>>>(p_bf, l1at, (const float*)nullptr, pp, 1024, 512, 512);
    // ee = e @ l1_w[512:] + l1_b (f32 out; l1_b folded here)
    gemm128_kernel<float><<<dim3(2, 4), 256, 0, stream>>>(e_bf, l1bt, l1_b, eeb, 256, 512, 512);

    // out[i,j,:] = relu(relu(pp[i]+ee[j]) @ w2 + b2)
    pair_mlp_kernel<<<dim3(2048, 4), 256, 0, stream>>>(pp, eeb, w2t, l2_b, out);
}